// Round 1
// 349.996 us; speedup vs baseline: 1.0438x; 1.0438x over previous
//
#include <hip/hip_runtime.h>

// ---------------------------------------------------------------------------
// WindowAttention fused kernel for MI355X (gfx950). FP32 I/O per reference:
//   x         [2048][49][256] f32      mask   [64][49][49] f32
//   qkv_w     [256][768] f32           qkv_b  [768] f32
//   proj_w    [256][256] f32           proj_b [256] f32
//   bias_table[169][8] f32             rel_index [2401] i32
//   out       [2048][49][256] f32
// Internals: bf16 MFMA (16x16x32), fp32 accumulate, exp2-domain softmax.
// v2: per-wave private attention (wave w owns head p*4+w end-to-end) --
//     removes the per-head single-wave scatter serialization and all 16
//     per-head __syncthreads.
// ---------------------------------------------------------------------------

typedef __attribute__((ext_vector_type(8))) short v8s;   // 8 x bf16 (4 VGPRs)
typedef __attribute__((ext_vector_type(4))) float v4f;   // MFMA accumulator

__device__ __forceinline__ unsigned short f2bf(float f) {   // RNE f32->bf16
    union { float f; unsigned int i; } v; v.f = f;
    unsigned int x = v.i;
    return (unsigned short)((x + 0x7fffu + ((x >> 16) & 1u)) >> 16);
}

#define NW1 196608              // W1f elements (48 tiles * 8 ksteps * 64 lanes * 8)
#define NW2 65536               // W2f elements (16 tiles * 8 ksteps * 64 lanes * 8)
#define NB1 768                 // B1v elements
#define NCB 1605632             // CBf elements (64*8*49*64), fp32
#define QSCALE_LOG2E 0.25503487f   // (1/sqrt(32)) * log2(e)
#define LOG2E 1.4426950408889634f

// ---------------------------------------------------------------------------
// Preprocessing: fragment-linear bf16 weights + fp32 combined bias/mask.
// (unchanged from v1 -- bitwise-identical outputs)
// ---------------------------------------------------------------------------
__global__ void wattn_preproc(const float* __restrict__ qkv_w,
                              const float* __restrict__ qkv_b,
                              const float* __restrict__ proj_w,
                              const float* __restrict__ bias_table,
                              const float* __restrict__ mask,
                              const int* __restrict__ rel_index,
                              unsigned short* __restrict__ W1f,
                              unsigned short* __restrict__ W2f,
                              float* __restrict__ B1v,
                              float* __restrict__ CBf)
{
    const int idx = blockIdx.x * 256 + threadIdx.x;
    if (idx < NW1) {
        const int j = idx & 7, l = (idx >> 3) & 63, s = (idx >> 9) & 7, T = idx >> 12;
        const int k = s * 32 + (l >> 4) * 8 + j;
        const int n = T * 16 + (l & 15);
        const int hh = n / 96, sub = n % 96;
        const int col = (sub < 32) ? (hh * 32 + sub)
                      : (sub < 64) ? (256 + hh * 32 + (sub - 32))
                                   : (512 + hh * 32 + (sub - 64));
        float v = qkv_w[k * 768 + col];
        if (sub < 32) v *= QSCALE_LOG2E;
        W1f[idx] = f2bf(v);
    } else if (idx < NW1 + NW2) {
        const int t = idx - NW1;
        const int j = t & 7, l = (t >> 3) & 63, s = (t >> 9) & 7, T = t >> 12;
        const int k = s * 32 + (l >> 4) * 8 + j;
        const int n = T * 16 + (l & 15);
        W2f[t] = f2bf(proj_w[k * 256 + n]);
    } else if (idx < NW1 + NW2 + NB1) {
        const int n = idx - NW1 - NW2;
        const int hh = n / 96, sub = n % 96;
        const int col = (sub < 32) ? (hh * 32 + sub)
                      : (sub < 64) ? (256 + hh * 32 + (sub - 32))
                                   : (512 + hh * 32 + (sub - 64));
        float v = qkv_b[col];
        if (sub < 32) v *= QSCALE_LOG2E;
        B1v[n] = v;
    } else {
        const int t = idx - (NW1 + NW2 + NB1);
        if (t < NCB) {
            const int c = t & 63;
            const int rr = t >> 6;
            const int r = rr % 49;
            const int q2 = rr / 49;
            const int hh = q2 & 7;
            const int w = q2 >> 3;
            float v;
            if (c < 49) {
                const int ri = rel_index[r * 49 + c];
                v = (bias_table[ri * 8 + hh] + mask[(w * 49 + r) * 49 + c]) * LOG2E;
            } else {
                v = -1e30f;
            }
            CBf[t] = v;
        }
    }
}

// ---------------------------------------------------------------------------
// Main fused kernel: one block (4 waves) per window.
// Per-wave private LDS region Wr (5832 shorts = 11664 B), overlaid lifetimes:
//   phase A: q [0,1960)  k [1960,3920)            ([49][40] each)
//   phase B: P [0,3528)  V^T [3528,5832)          (P [49][72], V [32][72])
// V is written only AFTER QK^T consumed k (V overlaps k's tail).
// ---------------------------------------------------------------------------
__global__ __launch_bounds__(256, 2)
void wattn_main(const float* __restrict__ x,
                const unsigned short* __restrict__ W1f,
                const float* __restrict__ B1v,
                const float* __restrict__ CB,
                const unsigned short* __restrict__ W2f,
                const float* __restrict__ proj_b,
                float* __restrict__ out)
{
    // LDS total = 7056 + 46656 + 25872 = 79584 B -> 2 blocks/CU (159168 <= 163840)
    __shared__ __align__(16) unsigned short xs[49 * 72];     // x chunk bf16 [row][64 cols + pad]
    __shared__ __align__(16) unsigned short wreg[4][5832];   // per-wave q/k then P/V
    __shared__ __align__(16) unsigned short Os[49 * 264];    // attn out [token][256]

    const int tid  = threadIdx.x;
    const int wave = tid >> 6;
    const int lane = tid & 63;
    const int quad = lane >> 4;
    const int l15  = lane & 15;
    const int b    = blockIdx.x;
    const int widx = b & 63;
    const float* xw = x + (long)b * 49 * 256;
    const v4f zero4 = {0.0f, 0.0f, 0.0f, 0.0f};
    unsigned short* Wr = wreg[wave];

    // A-frag row bases into xs (clamped pad rows)
    int arow[4];
    #pragma unroll
    for (int mt = 0; mt < 4; ++mt) {
        int m = mt * 16 + l15; if (m > 48) m = 48;
        arow[mt] = m * 72 + quad * 8;
    }

    // ---- two GEMM+attention phases; wave w owns head (p*4 + w) ----
    #pragma unroll 1
    for (int p = 0; p < 2; ++p) {
        v4f acc[6][4];
        #pragma unroll
        for (int i = 0; i < 6; ++i)
            #pragma unroll
            for (int mt = 0; mt < 4; ++mt) acc[i][mt] = zero4;

        const int T0 = p * 24 + wave * 6;
        const unsigned short* bb = W1f + T0 * 4096 + lane * 8;

        // QKV GEMM over K=256 in four 64-col chunks
        #pragma unroll 1
        for (int ch = 0; ch < 4; ++ch) {
            __syncthreads();   // previous consumers of xs done
            // stage x[:, ch*64 .. +64) -> bf16 LDS (coalesced float4 loads)
            for (int i = tid; i < 784; i += 256) {
                const int r = i >> 4, cq = i & 15;
                const float4 v = *reinterpret_cast<const float4*>(xw + r * 256 + ch * 64 + cq * 4);
                ushort4 o;
                o.x = f2bf(v.x); o.y = f2bf(v.y); o.z = f2bf(v.z); o.w = f2bf(v.w);
                *reinterpret_cast<ushort4*>(&xs[r * 72 + cq * 4]) = o;
            }
            __syncthreads();
            #pragma unroll
            for (int s = 0; s < 2; ++s) {
                v8s afr[4];
                #pragma unroll
                for (int mt = 0; mt < 4; ++mt)
                    afr[mt] = *reinterpret_cast<const v8s*>(&xs[arow[mt] + s * 32]);
                v8s bfr[6];
                #pragma unroll
                for (int i = 0; i < 6; ++i)
                    bfr[i] = *reinterpret_cast<const v8s*>(bb + i * 4096 + (ch * 2 + s) * 512);
                #pragma unroll
                for (int i = 0; i < 6; ++i)
                    #pragma unroll
                    for (int mt = 0; mt < 4; ++mt)
                        acc[i][mt] = __builtin_amdgcn_mfma_f32_16x16x32_bf16(afr[mt], bfr[i], acc[i][mt], 0, 0, 0);
            }
        }
        // qkv bias
        #pragma unroll
        for (int i = 0; i < 6; ++i) {
            const float bv = B1v[(T0 + i) * 16 + l15];
            #pragma unroll
            for (int mt = 0; mt < 4; ++mt) {
                acc[i][mt].x += bv; acc[i][mt].y += bv; acc[i][mt].z += bv; acc[i][mt].w += bv;
            }
        }

        // ================= per-wave attention (no block barriers) =============
        const int h = p * 4 + wave;

        // scatter q,k (C-layout acc -> row-major [token][d])
        #pragma unroll
        for (int i = 0; i < 4; ++i) {
            const int base = (i < 2) ? 0 : 1960;
            const int c = (i & 1) * 16 + l15;
            #pragma unroll
            for (int mt = 0; mt < 4; ++mt) {
                const int m0 = mt * 16 + quad * 4;
                #pragma unroll
                for (int r = 0; r < 4; ++r)
                    if (m0 + r < 49) Wr[base + (m0 + r) * 40 + c] = f2bf(acc[i][mt][r]);
            }
        }

        // QK^T: 4x4 tiles, K=32 in one step
        v8s aq[4], bk[4];
        #pragma unroll
        for (int t = 0; t < 4; ++t) {
            int rq = t * 16 + l15; if (rq > 48) rq = 48;
            aq[t] = *reinterpret_cast<const v8s*>(&Wr[rq * 40 + quad * 8]);
            bk[t] = *reinterpret_cast<const v8s*>(&Wr[1960 + rq * 40 + quad * 8]);
        }
        v4f sacc[4][4];
        #pragma unroll
        for (int mt = 0; mt < 4; ++mt)
            #pragma unroll
            for (int nt = 0; nt < 4; ++nt)
                sacc[mt][nt] = __builtin_amdgcn_mfma_f32_16x16x32_bf16(aq[mt], bk[nt], zero4, 0, 0, 0);

        // in-register softmax (exp2 domain) + P write (P overlays q/k region)
        const float* cbb = CB + ((long)widx * 8 + h) * 49 * 64;
        #pragma unroll
        for (int mt = 0; mt < 4; ++mt) {
            float pout[4][4];
            #pragma unroll
            for (int r = 0; r < 4; ++r) {
                const int m = mt * 16 + quad * 4 + r;
                const int mc = m > 48 ? 48 : m;
                float s0 = sacc[mt][0][r] + cbb[mc * 64 + l15];
                float s1 = sacc[mt][1][r] + cbb[mc * 64 + 16 + l15];
                float s2 = sacc[mt][2][r] + cbb[mc * 64 + 32 + l15];
                float s3 = sacc[mt][3][r] + cbb[mc * 64 + 48 + l15];
                float mx = fmaxf(fmaxf(s0, s1), fmaxf(s2, s3));
                #pragma unroll
                for (int off = 1; off < 16; off <<= 1) mx = fmaxf(mx, __shfl_xor(mx, off, 16));
                const float e0 = __builtin_exp2f(s0 - mx);
                const float e1 = __builtin_exp2f(s1 - mx);
                const float e2 = __builtin_exp2f(s2 - mx);
                const float e3 = __builtin_exp2f(s3 - mx);
                float sm = (e0 + e1) + (e2 + e3);
                #pragma unroll
                for (int off = 1; off < 16; off <<= 1) sm += __shfl_xor(sm, off, 16);
                const float rs = __builtin_amdgcn_rcpf(sm);
                pout[r][0] = e0 * rs; pout[r][1] = e1 * rs;
                pout[r][2] = e2 * rs; pout[r][3] = e3 * rs;
            }
            #pragma unroll
            for (int r = 0; r < 4; ++r) {
                const int m = mt * 16 + quad * 4 + r;
                if (m < 49) {
                    #pragma unroll
                    for (int nt = 0; nt < 4; ++nt)
                        Wr[m * 72 + nt * 16 + l15] = f2bf(pout[r][nt]);
                }
            }
        }

        // V^T write (after QK^T consumed k; V overlays k tail) + zero pad cols
        #pragma unroll
        for (int i = 4; i < 6; ++i) {
            const int d = (i - 4) * 16 + l15;
            #pragma unroll
            for (int mt = 0; mt < 4; ++mt) {
                const int m0 = mt * 16 + quad * 4;
                if (mt < 3) {
                    ushort4 pk;
                    pk.x = f2bf(acc[i][mt][0]); pk.y = f2bf(acc[i][mt][1]);
                    pk.z = f2bf(acc[i][mt][2]); pk.w = f2bf(acc[i][mt][3]);
                    *reinterpret_cast<ushort4*>(&Wr[3528 + d * 72 + m0]) = pk;
                } else if (quad == 0) {
                    Wr[3528 + d * 72 + 48] = f2bf(acc[i][mt][0]);
                }
            }
        }
        {   // zero V^T token-pad columns 49..63 (0*garbage could be NaN)
            const int d  = lane >> 1;
            const int c0 = 49 + (lane & 1) * 8;
            const int ce = (lane & 1) ? 64 : 57;
            for (int c = c0; c < ce; ++c) Wr[3528 + d * 72 + c] = 0;
        }

        // P @ V
        v8s bv2[2][2];
        #pragma unroll
        for (int n2 = 0; n2 < 2; ++n2)
            #pragma unroll
            for (int kt = 0; kt < 2; ++kt)
                bv2[n2][kt] = *reinterpret_cast<const v8s*>(&Wr[3528 + (n2 * 16 + l15) * 72 + kt * 32 + quad * 8]);
        #pragma unroll
        for (int mt = 0; mt < 4; ++mt) {
            int mrc = mt * 16 + l15; if (mrc > 48) mrc = 48;
            v4f oacc[2] = {zero4, zero4};
            #pragma unroll
            for (int kt = 0; kt < 2; ++kt) {
                const v8s ap = *reinterpret_cast<const v8s*>(&Wr[mrc * 72 + kt * 32 + quad * 8]);
                #pragma unroll
                for (int n2 = 0; n2 < 2; ++n2)
                    oacc[n2] = __builtin_amdgcn_mfma_f32_16x16x32_bf16(ap, bv2[n2][kt], oacc[n2], 0, 0, 0);
            }
            #pragma unroll
            for (int n2 = 0; n2 < 2; ++n2) {
                const int c = h * 32 + n2 * 16 + l15;
                #pragma unroll
                for (int r = 0; r < 4; ++r) {
                    const int m = mt * 16 + quad * 4 + r;
                    if (m < 49) Os[m * 264 + c] = f2bf(oacc[n2][r]);
                }
            }
        }
    } // p

    __syncthreads();

    // ---- projection: Os[49(->64)][256] @ proj_w -> out (fp32) ----
    v4f pacc[4][4];
    #pragma unroll
    for (int i = 0; i < 4; ++i)
        #pragma unroll
        for (int mt = 0; mt < 4; ++mt) pacc[i][mt] = zero4;

    int orow[4];
    #pragma unroll
    for (int mt = 0; mt < 4; ++mt) {
        int m = mt * 16 + l15; if (m > 48) m = 48;
        orow[mt] = m * 264 + quad * 8;
    }
    const unsigned short* wb = W2f + (wave * 4) * 4096 + lane * 8;

    #pragma unroll
    for (int s = 0; s < 8; ++s) {
        v8s afr[4];
        #pragma unroll
        for (int mt = 0; mt < 4; ++mt)
            afr[mt] = *reinterpret_cast<const v8s*>(&Os[orow[mt] + s * 32]);
        #pragma unroll
        for (int i = 0; i < 4; ++i) {
            const v8s bfp = *reinterpret_cast<const v8s*>(wb + i * 4096 + s * 512);
            #pragma unroll
            for (int mt = 0; mt < 4; ++mt)
                pacc[i][mt] = __builtin_amdgcn_mfma_f32_16x16x32_bf16(afr[mt], bfp, pacc[i][mt], 0, 0, 0);
        }
    }

    #pragma unroll
    for (int i = 0; i < 4; ++i) {
        const int c = (wave * 4 + i) * 16 + l15;
        const float pb = proj_b[c];
        #pragma unroll
        for (int mt = 0; mt < 4; ++mt) {
            #pragma unroll
            for (int r = 0; r < 4; ++r) {
                const int m = mt * 16 + quad * 4 + r;
                if (m < 49) out[((long)b * 49 + m) * 256 + c] = pacc[i][mt][r] + pb;
            }
        }
    }
}

// ---------------------------------------------------------------------------
extern "C" void kernel_launch(void* const* d_in, const int* in_sizes, int n_in,
                              void* d_out, int out_size, void* d_ws, size_t ws_size,
                              hipStream_t stream)
{
    const float* x          = (const float*)d_in[0];
    const float* mask       = (const float*)d_in[1];
    const float* qkv_w      = (const float*)d_in[2];
    const float* qkv_b      = (const float*)d_in[3];
    const float* proj_w     = (const float*)d_in[4];
    const float* proj_b     = (const float*)d_in[5];
    const float* bias_table = (const float*)d_in[6];
    const int*   rel_index  = (const int*)d_in[7];
    float* out = (float*)d_out;

    char* ws = (char*)d_ws;
    unsigned short* W1f = (unsigned short*)(ws);             // 393216 B
    unsigned short* W2f = (unsigned short*)(ws + 393216);    // 131072 B
    float*          B1v = (float*)(ws + 524288);             //   3072 B
    float*          CBf = (float*)(ws + 527360);             // 6422528 B (total ~6.95 MB)

    // 196608 + 65536 + 768 + 1605632 = 1868544 = 7299 * 256 exactly
    wattn_preproc<<<7299, 256, 0, stream>>>(qkv_w, qkv_b, proj_w, bias_table, mask,
                                            rel_index, W1f, W2f, B1v, CBf);
    wattn_main<<<2048, 256, 0, stream>>>(x, W1f, B1v, CBf, W2f, proj_b, out);
}